// Round 9
// baseline (469263.770 us; speedup 1.0000x reference)
//
#include <hip/hip_runtime.h>
#include <math.h>

// ---------------- problem constants ----------------
#define TSTEPS 400
#define KSP1 7
#define KSP2 8

// ---------------- workspace layout (float offsets) ----------------
#define OFF_XPRE  0u          // prenet out, BF16 [t][k][b]
#define OFF_PM    1638400u    // tanh(memory@wm) fp32 [b][t][128]
#define OFF_IN1T  2457600u    // lstm1 input rows 256..1791, [(k-256)][b]
#define OFF_IN2T  2506752u    // lstm2 input rows [k][b] (2560x32)
#define OFF_ZP1   2588672u    // coop: z1 [kh][b][4096] | fallback: partials [7][32][4096]
#define OFF_ZP2   3506176u    // coop: z2 [kh][b][4096] | fallback: partials [8][32][4096]
#define OFF_CTXP  4554752u    // ctx 4-deep [t&3][b][512]
#define OFF_H2B   4620288u    // h2 2-deep [parity][k][b]
#define OFF_C1    4685824u
#define OFF_C2    4718592u
#define OFF_ATTW  4751360u
#define OFF_CUM   4757760u
#define OFF_SYNC  4764160u    // inline grid barrier: [cnt, gen]
#define WS_FLOATS 4764164u

#define OUT_GATE  1024000
#define OUT_ALIGN 1036800

#define NBLK 256

__device__ __forceinline__ float sigf(float x)   { return 1.f / (1.f + __expf(-x)); }
__device__ __forceinline__ float tanhf_(float x) { return 1.f - 2.f / (__expf(2.f*x) + 1.f); }

// Inline grid barrier (agent-scope atomics, acq-rel). No function call ->
// no ABI spill of live VGPRs (R8 lesson: cg::grid.sync() is a real call).
__device__ __forceinline__ void gsync(unsigned* cnt, unsigned* gen, unsigned target, int tid) {
    __syncthreads();
    if (tid == 0) {
        unsigned prev = __hip_atomic_fetch_add(cnt, 1u, __ATOMIC_ACQ_REL, __HIP_MEMORY_SCOPE_AGENT);
        if (prev == (unsigned)(NBLK - 1)) {
            __hip_atomic_store(cnt, 0u, __ATOMIC_RELAXED, __HIP_MEMORY_SCOPE_AGENT);
            __hip_atomic_store(gen, target, __ATOMIC_RELEASE, __HIP_MEMORY_SCOPE_AGENT);
        } else {
            while (__hip_atomic_load(gen, __ATOMIC_ACQUIRE, __HIP_MEMORY_SCOPE_AGENT) < target)
                __builtin_amdgcn_s_sleep(1);
        }
    }
    __syncthreads();
}

// ---------------- prologue kernels ----------------
__global__ void __launch_bounds__(256) prenet_kernel(
    const float* __restrict__ dec, const float* __restrict__ w0, const float* __restrict__ b0,
    const float* __restrict__ w1, const float* __restrict__ b1, float* __restrict__ ws)
{
    __shared__ float s_in[80];
    __shared__ float s_h0[256];
    int t = blockIdx.x, b = blockIdx.y, tid = threadIdx.x;
    if (tid < 80) s_in[tid] = (t == 0) ? 0.f : dec[b*32000 + tid*400 + (t-1)];
    __syncthreads();
    float s = b0[tid];
    for (int m = 0; m < 80; ++m) s = fmaf(s_in[m], w0[m*256 + tid], s);
    s_h0[tid] = fmaxf(s, 0.f);
    __syncthreads();
    float s2 = b1[tid];
    for (int k = 0; k < 256; ++k) s2 = fmaf(s_h0[k], w1[k*256 + tid], s2);
    float v = fmaxf(s2, 0.f);
    unsigned u = __float_as_uint(v);
    u += 0x7fffu + ((u >> 16) & 1u);
    ((unsigned short*)(ws + OFF_XPRE))[(size_t)t*8192 + tid*32 + b] = (unsigned short)(u >> 16);
}

__global__ void __launch_bounds__(128) pmem_kernel(
    const float* __restrict__ mp, const float* __restrict__ wm, float* __restrict__ ws)
{
    int t = blockIdx.x, b = blockIdx.y, a = threadIdx.x;
    const float* mrow = mp + (b*200 + t)*512;
    float s = 0.f;
    for (int d = 0; d < 512; ++d) s = fmaf(mrow[d], wm[d*128 + a], s);
    ws[OFF_PM + (b*200 + t)*128 + a] = tanhf_(s);
}

__global__ void __launch_bounds__(256) zero_kernel(float* __restrict__ ws)
{
    int gid = blockIdx.x*256 + threadIdx.x, gsz = gridDim.x*256;
    for (int i = gid; i < 49152; i += gsz) ws[OFF_IN1T + i] = 0.f;
    for (int i = gid; i < 81920; i += gsz) ws[OFF_IN2T + i] = 0.f;
    for (int i = gid; i < 32768; i += gsz) { ws[OFF_C1 + i] = 0.f; ws[OFF_C2 + i] = 0.f; }
    for (int i = gid; i < 65536; i += gsz) { ws[OFF_CTXP + i] = 0.f; ws[OFF_H2B + i] = 0.f; }
    for (int i = gid; i < 6400;  i += gsz) { ws[OFF_ATTW + i] = 0.f; ws[OFF_CUM + i] = 0.f; }
    if (gid < 2) ((unsigned*)(ws + OFF_SYNC))[gid] = 0u;
}

// ================================================================
// Persistent decoder v2: weights register-resident, inline grid sync.
// 256 blocks x 1024 thr (1/CU, 16 waves). Block (c = bid>>1, kh = bid&1)
// owns cols c*32..+31 and k-half kh. Thread (jl = tid>>5, kq = tid&31):
// col = c*32+jl, k in {kh*KH + kq + 32*i}. Pinned: w1[28] + w2[40] = 68.
// x staged in LDS with XOR swizzle (float4 slot bg ^ (r&7)); jl-pairs in
// a wave read identical addresses (broadcast). z written per-half;
// phase2 sums 2 halves.
// ================================================================
__global__ void __launch_bounds__(1024, 4) decoder_kernel(
    const float* __restrict__ mp,
    const float* __restrict__ l1k, const float* __restrict__ l1r, const float* __restrict__ l1b,
    const float* __restrict__ l2k, const float* __restrict__ l2r, const float* __restrict__ l2b,
    const float* __restrict__ wq, const float* __restrict__ vvec,
    const float* __restrict__ lconv, const float* __restrict__ ldense,
    const float* __restrict__ fw, const float* __restrict__ fb,
    const float* __restrict__ sw, const float* __restrict__ sb,
    float* __restrict__ ws, float* __restrict__ out)
{
    __shared__ float s_mem[28672];            // 114.7 KB: x chunk | phase2 scratch
    const int tid = threadIdx.x, bid = blockIdx.x;
    const int jl = tid >> 5, kq = tid & 31;
    const int c = bid >> 1, kh = bid & 1;
    const int col = c*32 + jl;
    const int swz = kq & 7;                   // r & 7 == kq & 7 (r = kq + 32i)

    unsigned* scnt = (unsigned*)(ws + OFF_SYNC);
    unsigned* sgen = scnt + 1;
    unsigned bar = 0;

    float* z1v = ws + OFF_ZP1;                // [kh][b][4096]
    float* z2v = ws + OFF_ZP2;                // [kh][b][4096]
    float* in1m = ws + OFF_IN1T - 8192;       // valid for k >= 256
    float* in2T = ws + OFF_IN2T;
    float* ctxp = ws + OFF_CTXP;
    float* h2bb = ws + OFF_H2B;
    float* c1a  = ws + OFF_C1;
    float* c2a  = ws + OFF_C2;
    float* attwg = ws + OFF_ATTW;
    float* cumg  = ws + OFF_CUM;
    const float* pm = ws + OFF_PM;

    // ---- one-time: weights -> registers ----
    // gemv1 half: 896 k-rows; split 768 inside kh=0 at i=24 (32*24=768).
    float w1r[28];
#pragma unroll
    for (int i = 0; i < 28; ++i) {
        int kg = kh*896 + kq + 32*i;
        w1r[i] = (kg < 768) ? l1k[(size_t)kg*4096 + col] : l1r[(size_t)(kg - 768)*4096 + col];
    }
    // gemv2 half: 1280 k-rows; split 1536 inside kh=1 at i=8 (1280+256=1536).
    float w2r[40];
#pragma unroll
    for (int i = 0; i < 40; ++i) {
        int kg = kh*1280 + kq + 32*i;
        w2r[i] = (kg < 1536) ? l2k[(size_t)kg*4096 + col] : l2r[(size_t)(kg - 1536)*4096 + col];
    }
#pragma unroll
    for (int i = 0; i < 28; ++i) asm volatile("" : "+v"(w1r[i]));
#pragma unroll
    for (int i = 0; i < 40; ++i) asm volatile("" : "+v"(w2r[i]));

    for (int t = 0; t <= TSTEPS + 1; ++t) {
        // ======================= PHASE 1 =======================
        if (t < TSTEPS) {
            // -------- gemv1(t): this block's 896-row half, single chunk --------
            float4 acc[8];
#pragma unroll
            for (int g = 0; g < 8; ++g) acc[g] = make_float4(0.f,0.f,0.f,0.f);

            if (kh == 0) {
                // rows 0..255: bf16 xpre -> f32 (1024 uint4, one per thread)
                {
                    const uint4 p = ((const uint4*)((const unsigned short*)(ws + OFF_XPRE) + (size_t)t*8192))[tid];
                    const int r = tid >> 2;
                    const int bg = (tid & 3)*2;
                    float4 lo, hi;
                    lo.x = __uint_as_float(p.x << 16); lo.y = __uint_as_float(p.x & 0xffff0000u);
                    lo.z = __uint_as_float(p.y << 16); lo.w = __uint_as_float(p.y & 0xffff0000u);
                    hi.x = __uint_as_float(p.z << 16); hi.y = __uint_as_float(p.z & 0xffff0000u);
                    hi.z = __uint_as_float(p.w << 16); hi.w = __uint_as_float(p.w & 0xffff0000u);
                    ((float4*)s_mem)[r*8 + ((bg+0) ^ (r & 7))] = lo;
                    ((float4*)s_mem)[r*8 + ((bg+1) ^ (r & 7))] = hi;
                }
                // rows 256..895 from IN1T
                const float4* s1 = (const float4*)(ws + OFF_IN1T);
                for (int idx = tid; idx < 5120; idx += 1024) {
                    int r = 256 + (idx >> 3), bg = idx & 7;
                    ((float4*)s_mem)[r*8 + (bg ^ (r & 7))] = s1[idx];
                }
            } else {
                // rows 896..1791 from IN1T (local r = global - 896)
                const float4* s1 = (const float4*)(ws + OFF_IN1T);
                for (int idx = tid; idx < 7168; idx += 1024) {
                    int r = idx >> 3, bg = idx & 7;
                    ((float4*)s_mem)[r*8 + (bg ^ (r & 7))] = s1[5120 + idx];
                }
            }
            __syncthreads();
#pragma unroll
            for (int i = 0; i < 28; ++i) {
                const float w = w1r[i];
                const float4* x4 = (const float4*)s_mem + (kq + 32*i)*8;
#pragma unroll
                for (int g = 0; g < 8; ++g) {
                    float4 xv = x4[g ^ swz];
                    acc[g].x = fmaf(w, xv.x, acc[g].x); acc[g].y = fmaf(w, xv.y, acc[g].y);
                    acc[g].z = fmaf(w, xv.z, acc[g].z); acc[g].w = fmaf(w, xv.w, acc[g].w);
                }
            }
            __syncthreads();
            // butterfly reduce over kq (5 stages, within wave halves)
#pragma unroll
            for (int m = 1; m < 32; m <<= 1) {
#pragma unroll
                for (int g = 0; g < 8; ++g) {
                    acc[g].x += __shfl_xor(acc[g].x, m);
                    acc[g].y += __shfl_xor(acc[g].y, m);
                    acc[g].z += __shfl_xor(acc[g].z, m);
                    acc[g].w += __shfl_xor(acc[g].w, m);
                }
            }
            if (kq == 0) {
                float* zd = z1v + (size_t)kh*131072;
#pragma unroll
                for (int g = 0; g < 8; ++g) {
                    zd[(size_t)(4*g+0)*4096 + col] = acc[g].x;
                    zd[(size_t)(4*g+1)*4096 + col] = acc[g].y;
                    zd[(size_t)(4*g+2)*4096 + col] = acc[g].z;
                    zd[(size_t)(4*g+3)*4096 + col] = acc[g].w;
                }
            }
        }
        if (t >= 1 && t <= TSTEPS) {
            // -------- gemv2(t-1): 1280-row half in 2 chunks of 640 --------
            float4 acc[8];
#pragma unroll
            for (int g = 0; g < 8; ++g) acc[g] = make_float4(0.f,0.f,0.f,0.f);
            const float4* s2 = (const float4*)in2T;
#pragma unroll
            for (int cc = 0; cc < 2; ++cc) {
                const int base4 = (kh*1280 + cc*640)*8;
                for (int idx = tid; idx < 5120; idx += 1024) {
                    int r = idx >> 3, bg = idx & 7;
                    ((float4*)s_mem)[r*8 + (bg ^ (r & 7))] = s2[base4 + idx];
                }
                __syncthreads();
#pragma unroll
                for (int i = 0; i < 20; ++i) {
                    const float w = w2r[cc*20 + i];
                    const float4* x4 = (const float4*)s_mem + (kq + 32*i)*8;
#pragma unroll
                    for (int g = 0; g < 8; ++g) {
                        float4 xv = x4[g ^ swz];
                        acc[g].x = fmaf(w, xv.x, acc[g].x); acc[g].y = fmaf(w, xv.y, acc[g].y);
                        acc[g].z = fmaf(w, xv.z, acc[g].z); acc[g].w = fmaf(w, xv.w, acc[g].w);
                    }
                }
                __syncthreads();
            }
#pragma unroll
            for (int m = 1; m < 32; m <<= 1) {
#pragma unroll
                for (int g = 0; g < 8; ++g) {
                    acc[g].x += __shfl_xor(acc[g].x, m);
                    acc[g].y += __shfl_xor(acc[g].y, m);
                    acc[g].z += __shfl_xor(acc[g].z, m);
                    acc[g].w += __shfl_xor(acc[g].w, m);
                }
            }
            if (kq == 0) {
                float* zd = z2v + (size_t)kh*131072;
#pragma unroll
                for (int g = 0; g < 8; ++g) {
                    zd[(size_t)(4*g+0)*4096 + col] = acc[g].x;
                    zd[(size_t)(4*g+1)*4096 + col] = acc[g].y;
                    zd[(size_t)(4*g+2)*4096 + col] = acc[g].z;
                    zd[(size_t)(4*g+3)*4096 + col] = acc[g].w;
                }
            }
        }
        gsync(scnt, sgen, ++bar, tid);

        // ======================= PHASE 2 =======================
        {
            float* s_attw = s_mem;          // 200
            float* s_cum  = s_mem + 200;    // 200
            float* s_hid  = s_mem + 400;    // 1024
            float* s_q    = s_mem + 1424;   // 128
            float* s_ex   = s_mem + 1552;   // 200
            float* s_den  = s_mem + 1752;   // 4
            float* s_red  = s_mem + 1756;   // 1024
            float* s_co   = s_mem + 2780;   // 6600

            if (bid < 32) {
                if (t < TSTEPS) {
                    const int b = bid;
                    {   // LSTM1 gates (sum 2 z-halves)
                        int u = tid;
                        float zi = l1b[u]        + z1v[(size_t)b*4096 + u]        + z1v[131072 + (size_t)b*4096 + u];
                        float zf = l1b[1024 + u] + z1v[(size_t)b*4096 + 1024 + u] + z1v[131072 + (size_t)b*4096 + 1024 + u];
                        float zg = l1b[2048 + u] + z1v[(size_t)b*4096 + 2048 + u] + z1v[131072 + (size_t)b*4096 + 2048 + u];
                        float zo = l1b[3072 + u] + z1v[(size_t)b*4096 + 3072 + u] + z1v[131072 + (size_t)b*4096 + 3072 + u];
                        float cc2 = sigf(zf)*c1a[b*1024+u] + sigf(zi)*tanhf_(zg);
                        float h = sigf(zo)*tanhf_(cc2);
                        c1a[b*1024+u] = cc2;
                        s_hid[u] = h;
                        in1m[(768+u)*32 + b] = h;       // gemv1(t+1)
                        in2T[u*32 + b] = h;             // gemv2(t)
                    }
                    if (tid < 200) { s_attw[tid] = attwg[b*200 + tid]; s_cum[tid] = cumg[b*200 + tid]; }
                    __syncthreads();
                    {   // q partials: 8 k-strips x 128 a
                        int a = tid & 127, kq8 = tid >> 7;
                        float s = 0.f;
#pragma unroll 8
                        for (int k = kq8*128; k < kq8*128 + 128; ++k)
                            s = fmaf(s_hid[k], wq[k*128 + a], s);
                        s_red[tid] = s;
                    }
                    __syncthreads();
                    if (tid < 128) {
                        float s = 0.f;
#pragma unroll
                        for (int q = 0; q < 8; ++q) s += s_red[q*128 + tid];
                        s_q[tid] = tanhf_(s);
                    }
                    // location conv
                    for (int idx = tid; idx < 6400; idx += 1024) {
                        int tl = idx >> 5, f = idx & 31;
                        float s = 0.f;
                        for (int dw = 0; dw < 31; ++dw) {
                            int tg = tl - 15 + dw;
                            if (tg >= 0 && tg < 200) {
                                s = fmaf(s_attw[tg], lconv[(dw*2+0)*32 + f], s);
                                s = fmaf(s_cum[tg],  lconv[(dw*2+1)*32 + f], s);
                            }
                        }
                        s_co[tl*33 + f] = s;
                    }
                    __syncthreads();
                    // energies: 200 t x 4 lanes x 32 a
                    if (tid < 800) {
                        int tl = tid >> 2, aq = tid & 3;
                        const float* pmrow = pm + (b*200 + tl)*128;
                        float e = 0.f;
#pragma unroll 2
                        for (int a = aq*32; a < aq*32 + 32; ++a) {
                            float s = 0.f;
#pragma unroll
                            for (int f = 0; f < 32; ++f) s = fmaf(s_co[tl*33 + f], ldense[f*128 + a], s);
                            float en = tanhf_(s_q[a] + tanhf_(s) + pmrow[a]);
                            e = fmaf(en, vvec[a], e);
                        }
                        e += __shfl_xor(e, 1, 4);
                        e += __shfl_xor(e, 2, 4);
                        if (aq == 0) s_ex[tl] = __expf(e);
                    }
                    __syncthreads();
                    if (tid < 64) {
                        float s = 0.f;
                        for (int i = tid; i < 200; i += 64) s += s_ex[i];
                        for (int off = 32; off; off >>= 1) s += __shfl_down(s, off, 64);
                        if (tid == 0) s_den[0] = s;
                    }
                    __syncthreads();
                    if (tid < 200) {
                        float w = s_ex[tid] / s_den[0];
                        s_attw[tid] = w;
                        attwg[b*200 + tid] = w;
                        cumg[b*200 + tid] = s_cum[tid] + w;
                        out[OUT_ALIGN + (b*400 + t)*200 + tid] = w;
                    }
                    __syncthreads();
                    {   // context = att_w @ memory
                        int d = tid & 511, th = tid >> 9;
                        float s = 0.f;
#pragma unroll 10
                        for (int tt = th*100; tt < th*100 + 100; ++tt)
                            s = fmaf(s_attw[tt], mp[(b*200 + tt)*512 + d], s);
                        s_red[tid] = s;
                    }
                    __syncthreads();
                    if (tid < 512) {
                        float cv = s_red[tid] + s_red[512 + tid];
                        ctxp[(size_t)(t & 3)*16384 + b*512 + tid] = cv;
                        in1m[(256 + tid)*32 + b] = cv;     // gemv1(t+1)
                        in2T[(1024 + tid)*32 + b] = cv;    // gemv2(t)
                    }
                }
            } else if (bid < 64) {
                if (t >= 1 && t <= TSTEPS) {
                    const int b = bid - 32, t1 = t - 1;
                    float* h2b = h2bb + (size_t)(t1 & 1)*32768;
                    int u = tid;
                    float zi = l2b[u]        + z2v[(size_t)b*4096 + u]        + z2v[131072 + (size_t)b*4096 + u];
                    float zf = l2b[1024 + u] + z2v[(size_t)b*4096 + 1024 + u] + z2v[131072 + (size_t)b*4096 + 1024 + u];
                    float zg = l2b[2048 + u] + z2v[(size_t)b*4096 + 2048 + u] + z2v[131072 + (size_t)b*4096 + 2048 + u];
                    float zo = l2b[3072 + u] + z2v[(size_t)b*4096 + 3072 + u] + z2v[131072 + (size_t)b*4096 + 3072 + u];
                    float cc2 = sigf(zf)*c2a[b*1024+u] + sigf(zi)*tanhf_(zg);
                    float h = sigf(zo)*tanhf_(cc2);
                    c2a[b*1024+u] = cc2;
                    in2T[(1536+u)*32 + b] = h;      // gemv2(t)
                    h2b[u*32 + b] = h;              // mel/stop(t-1)
                }
            } else if (bid < 104) {
                if (t >= 2) {   // mel(t-2): 40 blocks x 2 cols, 16 kh x 96 k
                    const int t2 = t - 2;
                    const int mc = bid - 64;
                    const int m_l = tid & 1, b = (tid >> 1) & 31, khm = tid >> 6;
                    const int m = mc*2 + m_l;
                    const float* cp  = ctxp + (size_t)((t2 & 3)*32 + b)*512;
                    const float* h2b = h2bb + (size_t)(t2 & 1)*32768;
                    float s = 0.f;
#pragma unroll 4
                    for (int k = khm*96; k < khm*96 + 96; ++k) {
                        float dv = (k < 1024) ? h2b[k*32 + b] : cp[k - 1024];
                        s = fmaf(dv, fw[k*80 + m], s);
                    }
                    s_mem[tid] = s;   // tid = khm*64 + b*2 + m_l
                    __syncthreads();
                    if (tid < 64) {
                        float v = 0.f;
#pragma unroll
                        for (int k2 = 0; k2 < 16; ++k2) v += s_mem[k2*64 + tid];
                        int b2 = tid >> 1, m2 = mc*2 + (tid & 1);
                        out[(b2*80 + m2)*400 + t2] = v + fb[m2];
                    }
                }
            } else if (bid == 104) {
                if (t >= 2) {   // stop(t-2): 32 b x 32 kh x 48 k
                    const int t2 = t - 2;
                    const int b = tid >> 5, khs = tid & 31;
                    const float* cp  = ctxp + (size_t)((t2 & 3)*32 + b)*512;
                    const float* h2b = h2bb + (size_t)(t2 & 1)*32768;
                    float s = 0.f;
#pragma unroll 4
                    for (int k = khs*48; k < khs*48 + 48; ++k) {
                        float dv = (k < 1024) ? h2b[k*32 + b] : cp[k - 1024];
                        s = fmaf(dv, sw[k], s);
                    }
                    s_mem[tid] = s;   // tid = b*32 + khs
                    __syncthreads();
                    if (tid < 32) {
                        float z = 0.f;
#pragma unroll
                        for (int i = 0; i < 32; ++i) z += s_mem[tid*32 + i];
                        out[OUT_GATE + tid*400 + t2] = sigf(z + sb[0]);
                    }
                }
            }
        }
        gsync(scnt, sgen, ++bar, tid);
    }
}

// ================================================================
// Fallback per-step kernels (Round-5 verified) if coop launch rejected.
// ================================================================
__device__ __forceinline__ void gload_lds16(const float* g, float* l) {
    __builtin_amdgcn_global_load_lds((const __attribute__((address_space(1))) void*)g,
                                     (__attribute__((address_space(3))) void*)l, 16, 0, 0);
}

__global__ void __launch_bounds__(512, 4) kernel_P1(
    const float* __restrict__ l1k, const float* __restrict__ l1r,
    const float* __restrict__ l2k, const float* __restrict__ l2r,
    float* __restrict__ ws, int t)
{
    __shared__ float s_x[10240];
    __shared__ float s_w[8192];
    const int tid = threadIdx.x, bid = blockIdx.x;
    const int jq = tid & 31, bq = tid >> 5;
    const int lane = tid & 63, wid = tid >> 6;
    float4 a0 = make_float4(0.f,0.f,0.f,0.f), a1 = make_float4(0.f,0.f,0.f,0.f);

    if (bid < 224) {
        if (t >= TSTEPS) return;
        const int colgrp = bid & 31, ksp = bid >> 5;
        const int j = colgrp*128 + jq*4;
        const float* wbase = (ksp < 3) ? (l1k + (size_t)ksp*256*4096)
                                       : (l1r + (size_t)(ksp-3)*256*4096);
        const float* gsrc = wbase + colgrp*128 + (lane & 31)*4 + (size_t)(lane >> 5)*4096
                                  + (size_t)(wid*4)*4096;
        float* ldst = s_w + wid*4*128;
        {
            gload_lds16(gsrc,          ldst);
            gload_lds16(gsrc + 2*4096, ldst + 2*128);
        }
        if (ksp == 0) {
            const uint4* src = (const uint4*)((const unsigned short*)(ws + OFF_XPRE) + (size_t)t*8192);
            for (int i = tid; i < 1024; i += 512) {
                uint4 p = src[i];
                float* d = s_x + i*8;
                d[0] = __uint_as_float(p.x << 16); d[1] = __uint_as_float(p.x & 0xffff0000u);
                d[2] = __uint_as_float(p.y << 16); d[3] = __uint_as_float(p.y & 0xffff0000u);
                d[4] = __uint_as_float(p.z << 16); d[5] = __uint_as_float(p.z & 0xffff0000u);
                d[6] = __uint_as_float(p.w << 16); d[7] = __uint_as_float(p.w & 0xffff0000u);
            }
        } else {
            const float4* src = (const float4*)(ws + OFF_IN1T - 8192 + (size_t)ksp*256*32);
            float4* dst = (float4*)s_x;
            for (int i = tid; i < 2048; i += 512) dst[i] = src[i];
        }
        asm volatile("s_waitcnt vmcnt(0)" ::: "memory");
        __syncthreads();
        const float* xb = s_x + bq*2;
        const float* wjb = s_w + jq*4;
        for (int c = 0; c < 8; ++c) {
            if (c + 1 < 8) {
                const float* g = gsrc + (size_t)(c + 1)*32*4096;
                float* lp = ldst + ((c + 1) & 1)*4096;
                gload_lds16(g,          lp);
                gload_lds16(g + 2*4096, lp + 2*128);
            }
            const float* wch = wjb + (c & 1)*4096;
            const float* xch = xb + c*32*32;
#pragma unroll 8
            for (int kk = 0; kk < 32; ++kk) {
                float4 w = *(const float4*)(wch + kk*128);
                float2 x = *(const float2*)(xch + kk*32);
                a0.x = fmaf(x.x, w.x, a0.x); a0.y = fmaf(x.x, w.y, a0.y);
                a0.z = fmaf(x.x, w.z, a0.z); a0.w = fmaf(x.x, w.w, a0.w);
                a1.x = fmaf(x.y, w.x, a1.x); a1.y = fmaf(x.y, w.y, a1.y);
                a1.z = fmaf(x.y, w.z, a1.z); a1.w = fmaf(x.y, w.w, a1.w);
            }
            asm volatile("s_waitcnt vmcnt(0)" ::: "memory");
            __syncthreads();
        }
        float* zp1 = ws + OFF_ZP1;
        *(float4*)(zp1 + (size_t)(ksp*32 + bq*2 + 0)*4096 + j) = a0;
        *(float4*)(zp1 + (size_t)(ksp*32 + bq*2 + 1)*4096 + j) = a1;
    } else {
        if (t < 1 || t > TSTEPS) return;
        const int g2 = bid - 224;
        const int colgrp = g2 & 31, ksp = g2 >> 5;
        const int j = colgrp*128 + jq*4;
        const int kbase = ksp*320;
        float* ldst = s_w + wid*4*128;
        {
            int kg = kbase;
            const float* wb2 = (kg < 1536) ? (l2k + (size_t)kg*4096)
                                           : (l2r + (size_t)(kg - 1536)*4096);
            const float* g = wb2 + colgrp*128 + (lane & 31)*4 + (size_t)(lane >> 5)*4096
                                 + (size_t)(wid*4)*4096;
            gload_lds16(g,          ldst);
            gload_lds16(g + 2*4096, ldst + 2*128);
        }
        {
            const float4* src = (const float4*)(ws + OFF_IN2T + (size_t)kbase*32);
            float4* dst = (float4*)s_x;
            for (int i = tid; i < 2560; i += 512) dst[i] = src[i];
        }
        asm volatile("s_waitcnt vmcnt(0)" ::: "memory");
        __syncthreads();
        const float* xb = s_x + bq*2;
        const float* wjb = s_w + jq*4;
        for (int c = 0; c < 10; ++c) {
            if (c + 1 < 10) {
                int kg = kbase + (c + 1)*32;
                const float* wb2 = (kg < 1536) ? (l2k + (size_t)kg*4096)
                                               : (l2r + (size_t)(kg - 1536)*4096);
                const float* g = wb2 + colgrp*128 + (lane & 31)*4 + (size_t)(lane >> 5)*4096
                                     + (size_t)(wid*4)*4096;
                float* lp = ldst + ((c + 1) & 1)*4096;
                gload_lds16(g,          lp);
                gload_lds16(g + 2*4096, lp + 2*128);
            }
            const float* wch = wjb + (c & 1)*4096;
            const float* xch = xb + c*32*32;
#pragma unroll 8
            for (int kk = 0; kk < 32; ++kk) {
                float4 w = *(const float4*)(wch + kk*128);
                float2 x = *(const float2*)(xch + kk*32);
                a0.x = fmaf(x.x, w.x, a0.x); a0.y = fmaf(x.x, w.y, a0.y);
                a0.z = fmaf(x.x, w.z, a0.z); a0.w = fmaf(x.x, w.w, a0.w);
                a1.x = fmaf(x.y, w.x, a1.x); a1.y = fmaf(x.y, w.y, a1.y);
                a1.z = fmaf(x.y, w.z, a1.z); a1.w = fmaf(x.y, w.w, a1.w);
            }
            asm volatile("s_waitcnt vmcnt(0)" ::: "memory");
            __syncthreads();
        }
        float* zp2 = ws + OFF_ZP2;
        *(float4*)(zp2 + (size_t)(ksp*32 + bq*2 + 0)*4096 + j) = a0;
        *(float4*)(zp2 + (size_t)(ksp*32 + bq*2 + 1)*4096 + j) = a1;
    }
}

__global__ void __launch_bounds__(1024) kernel_P2(
    const float* __restrict__ mp, const float* __restrict__ l1b, const float* __restrict__ l2b,
    const float* __restrict__ wq, const float* __restrict__ vvec,
    const float* __restrict__ lconv, const float* __restrict__ ldense,
    const float* __restrict__ fw, const float* __restrict__ fb,
    const float* __restrict__ sw, const float* __restrict__ sb,
    float* __restrict__ ws, float* __restrict__ out, int t)
{
    __shared__ float s_attw[200], s_cum[200];
    __shared__ float s_hid[1024], s_q[128], s_ex[200], s_den[1];
    __shared__ float s_co[200*33];
    __shared__ float s_red[1024];
    const int tid = threadIdx.x, bid = blockIdx.x;
    float* in1m = ws + OFF_IN1T - 8192;
    float* in2T = ws + OFF_IN2T;
    float* zp1  = ws + OFF_ZP1;
    float* zp2  = ws + OFF_ZP2;
    float* ctxp = ws + OFF_CTXP;
    float* h2bb = ws + OFF_H2B;
    float* c1a  = ws + OFF_C1;
    float* c2a  = ws + OFF_C2;
    float* attw = ws + OFF_ATTW;
    float* cum  = ws + OFF_CUM;
    const float* pm = ws + OFF_PM;

    if (bid < 32) {
        if (t >= TSTEPS) return;
        const int b = bid;
        {
            int u = tid;
            float zi = l1b[u], zf = l1b[1024+u], zg = l1b[2048+u], zo = l1b[3072+u];
#pragma unroll
            for (int kc = 0; kc < KSP1; ++kc) {
                const float* zr = zp1 + (size_t)(kc*32 + b)*4096;
                zi += zr[u]; zf += zr[1024+u]; zg += zr[2048+u]; zo += zr[3072+u];
            }
            float c = sigf(zf)*c1a[b*1024+u] + sigf(zi)*tanhf_(zg);
            float h = sigf(zo)*tanhf_(c);
            c1a[b*1024+u] = c;
            s_hid[u] = h;
            in1m[(768+u)*32 + b] = h;
            in2T[u*32 + b] = h;
        }
        if (tid < 200) { s_attw[tid] = attw[b*200 + tid]; s_cum[tid] = cum[b*200 + tid]; }
        __syncthreads();
        {
            int a = tid & 127, kq = tid >> 7;
            float s = 0.f;
#pragma unroll 8
            for (int k = kq*128; k < kq*128 + 128; ++k)
                s = fmaf(s_hid[k], wq[k*128 + a], s);
            s_red[tid] = s;
        }
        __syncthreads();
        if (tid < 128) {
            float s = 0.f;
#pragma unroll
            for (int q = 0; q < 8; ++q) s += s_red[q*128 + tid];
            s_q[tid] = tanhf_(s);
        }
        for (int idx = tid; idx < 6400; idx += 1024) {
            int tl = idx >> 5, f = idx & 31;
            float s = 0.f;
            for (int dw = 0; dw < 31; ++dw) {
                int tg = tl - 15 + dw;
                if (tg >= 0 && tg < 200) {
                    s = fmaf(s_attw[tg], lconv[(dw*2+0)*32 + f], s);
                    s = fmaf(s_cum[tg],  lconv[(dw*2+1)*32 + f], s);
                }
            }
            s_co[tl*33 + f] = s;
        }
        __syncthreads();
        if (tid < 800) {
            int tl = tid >> 2, aq = tid & 3;
            const float* pmrow = pm + (b*200 + tl)*128;
            float e = 0.f;
#pragma unroll 2
            for (int a = aq*32; a < aq*32 + 32; ++a) {
                float s = 0.f;
#pragma unroll
                for (int f = 0; f < 32; ++f) s = fmaf(s_co[tl*33 + f], ldense[f*128 + a], s);
                float en = tanhf_(s_q[a] + tanhf_(s) + pmrow[a]);
                e = fmaf(en, vvec[a], e);
            }
            e += __shfl_xor(e, 1, 4);
            e += __shfl_xor(e, 2, 4);
            if (aq == 0) s_ex[tl] = __expf(e);
        }
        __syncthreads();
        if (tid < 64) {
            float s = 0.f;
            for (int i = tid; i < 200; i += 64) s += s_ex[i];
            for (int off = 32; off; off >>= 1) s += __shfl_down(s, off, 64);
            if (tid == 0) s_den[0] = s;
        }
        __syncthreads();
        if (tid < 200) {
            float w = s_ex[tid] / s_den[0];
            s_attw[tid] = w;
            attw[b*200 + tid] = w;
            cum[b*200 + tid] = s_cum[tid] + w;
            out[OUT_ALIGN + (b*400 + t)*200 + tid] = w;
        }
        __syncthreads();
        {
            int d = tid & 511, th = tid >> 9;
            float s = 0.f;
#pragma unroll 10
            for (int tt = th*100; tt < th*100 + 100; ++tt)
                s = fmaf(s_attw[tt], mp[(b*200 + tt)*512 + d], s);
            s_red[tid] = s;
        }
        __syncthreads();
        if (tid < 512) {
            float cv = s_red[tid] + s_red[512 + tid];
            ctxp[(size_t)(t & 3)*16384 + b*512 + tid] = cv;
            in1m[(256 + tid)*32 + b] = cv;
            in2T[(1024 + tid)*32 + b] = cv;
        }
    } else if (bid < 64) {
        if (t < 1 || t > TSTEPS) return;
        const int b = bid - 32, t1 = t - 1;
        float* h2b = h2bb + (size_t)(t1 & 1)*32768;
        int u = tid;
        float zi = l2b[u], zf = l2b[1024+u], zg = l2b[2048+u], zo = l2b[3072+u];
#pragma unroll
        for (int kc = 0; kc < KSP2; ++kc) {
            const float* zr = zp2 + (size_t)(kc*32 + b)*4096;
            zi += zr[u]; zf += zr[1024+u]; zg += zr[2048+u]; zo += zr[3072+u];
        }
        float c = sigf(zf)*c2a[b*1024+u] + sigf(zi)*tanhf_(zg);
        float h = sigf(zo)*tanhf_(c);
        c2a[b*1024+u] = c;
        in2T[(1536+u)*32 + b] = h;
        h2b[u*32 + b] = h;
    } else if (bid < 74) {
        if (t < 2) return;
        const int t2 = t - 2;
        const int mc = bid - 64;
        const int m_l = tid & 7, b = (tid >> 3) & 31, kh = tid >> 8;
        const int m = mc*8 + m_l;
        const float* cp = ctxp + (size_t)((t2 & 3)*32 + b)*512;
        const float* h2b = h2bb + (size_t)(t2 & 1)*32768;
        float s = 0.f;
#pragma unroll 8
        for (int k = kh*384; k < kh*384 + 384; ++k) {
            float dv = (k < 1024) ? h2b[k*32 + b] : cp[k - 1024];
            s = fmaf(dv, fw[k*80 + m], s);
        }
        s_red[tid] = s;
        __syncthreads();
        if (tid < 256) {
            float v4 = s_red[tid] + s_red[256+tid] + s_red[512+tid] + s_red[768+tid];
            int b2 = tid >> 3, m2 = mc*8 + (tid & 7);
            out[(b2*80 + m2)*400 + t2] = v4 + fb[m2];
        }
    } else {
        if (t < 2) return;
        const int t2 = t - 2;
        const int b = tid >> 5, kh = tid & 31;
        const float* cp = ctxp + (size_t)((t2 & 3)*32 + b)*512;
        const float* h2b = h2bb + (size_t)(t2 & 1)*32768;
        float s = 0.f;
#pragma unroll 8
        for (int k = kh*48; k < kh*48 + 48; ++k) {
            float dv = (k < 1024) ? h2b[k*32 + b] : cp[k - 1024];
            s = fmaf(dv, sw[k], s);
        }
        s_red[b*32 + kh] = s;
        __syncthreads();
        if (tid < 32) {
            float z = 0.f;
#pragma unroll
            for (int i = 0; i < 32; ++i) z += s_red[tid*32 + i];
            out[OUT_GATE + tid*400 + t2] = sigf(z + sb[0]);
        }
    }
}

extern "C" void kernel_launch(void* const* d_in, const int* in_sizes, int n_in,
                              void* d_out, int out_size, void* d_ws, size_t ws_size,
                              hipStream_t stream) {
    (void)in_sizes; (void)n_in; (void)out_size;
    const float* mp    = (const float*)d_in[0];
    const float* dec   = (const float*)d_in[1];
    const float* pw0   = (const float*)d_in[2];
    const float* pb0   = (const float*)d_in[3];
    const float* pw1   = (const float*)d_in[4];
    const float* pb1   = (const float*)d_in[5];
    const float* l1k   = (const float*)d_in[6];
    const float* l1r   = (const float*)d_in[7];
    const float* l1b   = (const float*)d_in[8];
    const float* l2k   = (const float*)d_in[9];
    const float* l2r   = (const float*)d_in[10];
    const float* l2b   = (const float*)d_in[11];
    const float* wq    = (const float*)d_in[12];
    const float* wm    = (const float*)d_in[13];
    const float* vvec  = (const float*)d_in[14];
    const float* lconv = (const float*)d_in[15];
    const float* ldns  = (const float*)d_in[16];
    const float* fw    = (const float*)d_in[17];
    const float* fb    = (const float*)d_in[18];
    const float* sw    = (const float*)d_in[19];
    const float* sb    = (const float*)d_in[20];
    float* ws  = (float*)d_ws;
    float* out = (float*)d_out;

    if (ws_size < (size_t)WS_FLOATS * sizeof(float)) return;

    prenet_kernel<<<dim3(400, 32), 256, 0, stream>>>(dec, pw0, pb0, pw1, pb1, ws);
    pmem_kernel  <<<dim3(200, 32), 128, 0, stream>>>(mp, wm, ws);
    zero_kernel  <<<256, 256, 0, stream>>>(ws);

    void* kargs[] = {
        (void*)&mp, (void*)&l1k, (void*)&l1r, (void*)&l1b,
        (void*)&l2k, (void*)&l2r, (void*)&l2b,
        (void*)&wq, (void*)&vvec, (void*)&lconv, (void*)&ldns,
        (void*)&fw, (void*)&fb, (void*)&sw, (void*)&sb,
        (void*)&ws, (void*)&out
    };
    hipError_t err = hipLaunchCooperativeKernel((const void*)decoder_kernel,
                                                dim3(NBLK), dim3(1024), kargs, 0, stream);
    if (err != hipSuccess) {
        for (int t = 0; t <= TSTEPS; ++t) {
            kernel_P1<<<480, 512, 0, stream>>>(l1k, l1r, l2k, l2r, ws, t);
            kernel_P2<<<75, 1024, 0, stream>>>(mp, l1b, l2b, wq, vvec, lconv, ldns,
                                               fw, fb, sw, sb, ws, out, t);
        }
        kernel_P2<<<75, 1024, 0, stream>>>(mp, l1b, l2b, wq, vvec, lconv, ldns,
                                           fw, fb, sw, sb, ws, out, TSTEPS + 1);
    }
}

// Round 10
// 98298.981 us; speedup vs baseline: 4.7738x; 4.7738x over previous
//
#include <hip/hip_runtime.h>
#include <math.h>

// ---------------- problem constants ----------------
#define TSTEPS 400

// GEMV1: K1=1792 (x 0..255 bf16 | ctx 256..767 | h1 768..1791), W split at 768
//   224 blocks = 32 colgrp(128 cols) x 7 ksp(256 k = 4 ksub x 64)
// GEMV2: K2=2560 (h1 0..1023 | ctx 1024..1535 | h2 1536..2559), W split at 1536
//   256 blocks = 32 colgrp(128 cols) x 8 ksp(320 k = 4 ksub x 80)
#define KSP1 7
#define KSP2 8

// ---------------- workspace layout (float offsets) ----------------
#define OFF_XPRE  0u          // prenet out, BF16 [t][k][b]: 400*256*32 ushort
#define OFF_PM    1638400u    // tanh(memory@wm) fp32 [b][t][128]
#define OFF_IN1T  2457600u    // lstm1 input rows 256..1791, [(k-256)][b]
#define OFF_IN2T  2506752u    // lstm2 input rows [k][b]
#define OFF_ZP1   2588672u    // gemv1 partials [7][32][4096]
#define OFF_ZP2   3506176u    // gemv2 partials [8][32][4096]
#define OFF_CTXP  4554752u    // ctx 4-deep buffer [t&3][b][512]
#define OFF_H2B   4620288u    // h2 2-deep buffer [parity][k][b]
#define OFF_C1    4685824u    // c1 [b][1024]
#define OFF_C2    4718592u    // c2
#define OFF_ATTW  4751360u    // att_w [b][200]
#define OFF_CUM   4757760u    // att_w_cum
#define WS_FLOATS 4764160u    // 19.06 MB

// output layout (floats)
#define OUT_GATE  1024000   // 32*80*400
#define OUT_ALIGN 1036800   // + 32*400

__device__ __forceinline__ float sigf(float x)   { return 1.f / (1.f + __expf(-x)); }
__device__ __forceinline__ float tanhf_(float x) { return 1.f - 2.f / (__expf(2.f*x) + 1.f); }

// ---------------- P1: prenet for all 400 frames -> bf16 [t][k][b] ----------------
__global__ void __launch_bounds__(256) prenet_kernel(
    const float* __restrict__ dec, const float* __restrict__ w0, const float* __restrict__ b0,
    const float* __restrict__ w1, const float* __restrict__ b1, float* __restrict__ ws)
{
    __shared__ float s_in[80];
    __shared__ float s_h0[256];
    int t = blockIdx.x, b = blockIdx.y, tid = threadIdx.x;
    if (tid < 80) s_in[tid] = (t == 0) ? 0.f : dec[b*32000 + tid*400 + (t-1)];
    __syncthreads();
    float s = b0[tid];
    for (int m = 0; m < 80; ++m) s = fmaf(s_in[m], w0[m*256 + tid], s);
    s_h0[tid] = fmaxf(s, 0.f);
    __syncthreads();
    float s2 = b1[tid];
    for (int k = 0; k < 256; ++k) s2 = fmaf(s_h0[k], w1[k*256 + tid], s2);
    float v = fmaxf(s2, 0.f);
    unsigned u = __float_as_uint(v);
    u += 0x7fffu + ((u >> 16) & 1u);                     // RNE to bf16
    ((unsigned short*)(ws + OFF_XPRE))[(size_t)t*8192 + tid*32 + b] = (unsigned short)(u >> 16);
}

// ---------------- P2: processed_memory = tanh(memory @ wm), fp32 ----------------
__global__ void __launch_bounds__(128) pmem_kernel(
    const float* __restrict__ mp, const float* __restrict__ wm, float* __restrict__ ws)
{
    int t = blockIdx.x, b = blockIdx.y, a = threadIdx.x;
    const float* mrow = mp + (b*200 + t)*512;
    float s = 0.f;
    for (int d = 0; d < 512; ++d) s = fmaf(mrow[d], wm[d*128 + a], s);
    ws[OFF_PM + (b*200 + t)*128 + a] = tanhf_(s);
}

// ---------------- P3: zero recurrent state ----------------
__global__ void __launch_bounds__(256) zero_kernel(float* __restrict__ ws)
{
    int gid = blockIdx.x*256 + threadIdx.x, gsz = gridDim.x*256;
    for (int i = gid; i < 49152; i += gsz) ws[OFF_IN1T + i] = 0.f;
    for (int i = gid; i < 81920; i += gsz) ws[OFF_IN2T + i] = 0.f;
    for (int i = gid; i < 32768; i += gsz) { ws[OFF_C1 + i] = 0.f; ws[OFF_C2 + i] = 0.f; }
    for (int i = gid; i < 65536; i += gsz) { ws[OFF_CTXP + i] = 0.f; ws[OFF_H2B + i] = 0.f; }
    for (int i = gid; i < 6400;  i += gsz) { ws[OFF_ATTW + i] = 0.f; ws[OFF_CUM + i] = 0.f; }
}

#define FMA8(XA, XB, W)                                                                               \
    a[0].x = fmaf(XA.x, W.x, a[0].x); a[0].y = fmaf(XA.x, W.y, a[0].y); a[0].z = fmaf(XA.x, W.z, a[0].z); a[0].w = fmaf(XA.x, W.w, a[0].w); \
    a[1].x = fmaf(XA.y, W.x, a[1].x); a[1].y = fmaf(XA.y, W.y, a[1].y); a[1].z = fmaf(XA.y, W.z, a[1].z); a[1].w = fmaf(XA.y, W.w, a[1].w); \
    a[2].x = fmaf(XA.z, W.x, a[2].x); a[2].y = fmaf(XA.z, W.y, a[2].y); a[2].z = fmaf(XA.z, W.z, a[2].z); a[2].w = fmaf(XA.z, W.w, a[2].w); \
    a[3].x = fmaf(XA.w, W.x, a[3].x); a[3].y = fmaf(XA.w, W.y, a[3].y); a[3].z = fmaf(XA.w, W.z, a[3].z); a[3].w = fmaf(XA.w, W.w, a[3].w); \
    a[4].x = fmaf(XB.x, W.x, a[4].x); a[4].y = fmaf(XB.x, W.y, a[4].y); a[4].z = fmaf(XB.x, W.z, a[4].z); a[4].w = fmaf(XB.x, W.w, a[4].w); \
    a[5].x = fmaf(XB.y, W.x, a[5].x); a[5].y = fmaf(XB.y, W.y, a[5].y); a[5].z = fmaf(XB.y, W.z, a[5].z); a[5].w = fmaf(XB.y, W.w, a[5].w); \
    a[6].x = fmaf(XB.z, W.x, a[6].x); a[6].y = fmaf(XB.z, W.y, a[6].y); a[6].z = fmaf(XB.z, W.z, a[6].z); a[6].w = fmaf(XB.z, W.w, a[6].w); \
    a[7].x = fmaf(XB.w, W.x, a[7].x); a[7].y = fmaf(XB.w, W.y, a[7].y); a[7].z = fmaf(XB.w, W.z, a[7].z); a[7].w = fmaf(XB.w, W.w, a[7].w)

// ================================================================
// Phase kernel P1: gemv1(t) [blocks 0..223] || gemv2(t-1) [blocks 224..479]
// (Round-3 verified 76 ms configuration, verbatim.)
// 512 thr = 32 jq(4 cols) x 4 bgrp(8 b) x 4 ksub.
// Activation slice staged in LDS (vmcnt queue = weight stream only);
// weights manually prefetched 4-deep. LDS union: x-stage then acc-combine.
// ================================================================
__global__ void __launch_bounds__(512, 4) kernel_P1(
    const float* __restrict__ l1k, const float* __restrict__ l1r,
    const float* __restrict__ l2k, const float* __restrict__ l2r,
    float* __restrict__ ws, int t)
{
    __shared__ float s_lds[12288];   // union: x-stage (<=10240) | acc 3x4096
    const int tid = threadIdx.x, bid = blockIdx.x;
    const int jq = tid & 31, bgrp = (tid >> 5) & 3, ksub = tid >> 7;
    const int b0 = bgrp*8;
    float4 a[8];
#pragma unroll
    for (int i = 0; i < 8; ++i) a[i] = make_float4(0.f, 0.f, 0.f, 0.f);

    if (bid < 224) {
        if (t >= TSTEPS) return;
        // -------- gemv1(t): block = 128 cols x 256 k --------
        const int colgrp = bid & 31, ksp = bid >> 5;
        const int j = colgrp*128 + jq*4;

        // ---- stage x slice (256 k x 32 b floats = 8192) into LDS ----
        if (ksp == 0) {
            // bf16 prenet frame -> f32
            const uint4* src = (const uint4*)((const unsigned short*)(ws + OFF_XPRE) + (size_t)t*8192);
            for (int i = tid; i < 1024; i += 512) {
                uint4 p = src[i];
                float* d = s_lds + i*8;
                d[0] = __uint_as_float(p.x << 16); d[1] = __uint_as_float(p.x & 0xffff0000u);
                d[2] = __uint_as_float(p.y << 16); d[3] = __uint_as_float(p.y & 0xffff0000u);
                d[4] = __uint_as_float(p.z << 16); d[5] = __uint_as_float(p.z & 0xffff0000u);
                d[6] = __uint_as_float(p.w << 16); d[7] = __uint_as_float(p.w & 0xffff0000u);
            }
        } else {
            const float4* src = (const float4*)(ws + OFF_IN1T - 8192 + (size_t)ksp*256*32);
            float4* dst = (float4*)s_lds;
            for (int i = tid; i < 2048; i += 512) dst[i] = src[i];
        }
        __syncthreads();

        // ---- FMA loop: 64 k per ksub, 4-deep weight prefetch ----
        // 64-k ranges are 64-aligned; the 768 boundary is 64-aligned -> no straddle
        const int kl0 = ksub*64;                    // local k in [0,256)
        const int kg0 = ksp*256 + kl0;              // global k
        const float* wb = (kg0 < 768) ? (l1k + (size_t)kg0*4096 + j)
                                      : (l1r + (size_t)(kg0 - 768)*4096 + j);
        float4 wbuf[4];
#pragma unroll
        for (int i = 0; i < 4; ++i) wbuf[i] = *(const float4*)(wb + (size_t)i*4096);
        for (int kk = 0; kk < 60; kk += 4) {
            float4 wn[4];
#pragma unroll
            for (int i = 0; i < 4; ++i) wn[i] = *(const float4*)(wb + (size_t)(kk + 4 + i)*4096);
#pragma unroll
            for (int i = 0; i < 4; ++i) {
                const float* xp = s_lds + (kl0 + kk + i)*32 + b0;
                float4 xa = *(const float4*)xp;
                float4 xb = *(const float4*)(xp + 4);
                FMA8(xa, xb, wbuf[i]);
            }
#pragma unroll
            for (int i = 0; i < 4; ++i) wbuf[i] = wn[i];
        }
#pragma unroll
        for (int i = 0; i < 4; ++i) {
            const float* xp = s_lds + (kl0 + 60 + i)*32 + b0;
            float4 xa = *(const float4*)xp;
            float4 xb = *(const float4*)(xp + 4);
            FMA8(xa, xb, wbuf[i]);
        }

        // ---- combine ksubs via LDS (reuse s_lds after barrier) ----
        __syncthreads();
        if (ksub) {
#pragma unroll
            for (int i = 0; i < 8; ++i)
                *(float4*)(s_lds + (ksub-1)*4096 + (b0 + i)*128 + jq*4) = a[i];
        }
        __syncthreads();
        if (!ksub) {
            float* zp1 = ws + OFF_ZP1;
#pragma unroll
            for (int i = 0; i < 8; ++i) {
                float4 r0 = *(const float4*)(s_lds +         (b0 + i)*128 + jq*4);
                float4 r1 = *(const float4*)(s_lds +  4096 + (b0 + i)*128 + jq*4);
                float4 r2 = *(const float4*)(s_lds +  8192 + (b0 + i)*128 + jq*4);
                a[i].x += r0.x + r1.x + r2.x; a[i].y += r0.y + r1.y + r2.y;
                a[i].z += r0.z + r1.z + r2.z; a[i].w += r0.w + r1.w + r2.w;
                *(float4*)(zp1 + (size_t)(ksp*32 + b0 + i)*4096 + j) = a[i];
            }
        }
    } else {
        if (t < 1 || t > TSTEPS) return;
        // -------- gemv2(t-1): block = 128 cols x 320 k --------
        const int g = bid - 224;
        const int colgrp = g & 31, ksp = g >> 5;
        const int j = colgrp*128 + jq*4;

        // ---- stage x slice (320 k x 32 b = 10240 floats) into LDS ----
        {
            const float4* src = (const float4*)(ws + OFF_IN2T + (size_t)ksp*320*32);
            float4* dst = (float4*)s_lds;
            for (int i = tid; i < 2560; i += 512) dst[i] = src[i];
        }
        __syncthreads();

        // ---- FMA loop: 80 k per ksub, 4-deep weight prefetch ----
        // 80-k chunks can straddle the 1536 split -> per-load row select
        const int kl0 = ksub*80;                    // local k in [0,320)
        const int kg0 = ksp*320 + kl0;              // global k
        float4 wbuf[4];
#pragma unroll
        for (int i = 0; i < 4; ++i) {
            int kg = kg0 + i;
            const float* wr = (kg < 1536) ? (l2k + (size_t)kg*4096)
                                          : (l2r + (size_t)(kg - 1536)*4096);
            wbuf[i] = *(const float4*)(wr + j);
        }
        for (int kk = 0; kk < 76; kk += 4) {
            float4 wn[4];
#pragma unroll
            for (int i = 0; i < 4; ++i) {
                int kg = kg0 + kk + 4 + i;
                const float* wr = (kg < 1536) ? (l2k + (size_t)kg*4096)
                                              : (l2r + (size_t)(kg - 1536)*4096);
                wn[i] = *(const float4*)(wr + j);
            }
#pragma unroll
            for (int i = 0; i < 4; ++i) {
                const float* xp = s_lds + (kl0 + kk + i)*32 + b0;
                float4 xa = *(const float4*)xp;
                float4 xb = *(const float4*)(xp + 4);
                FMA8(xa, xb, wbuf[i]);
            }
#pragma unroll
            for (int i = 0; i < 4; ++i) wbuf[i] = wn[i];
        }
#pragma unroll
        for (int i = 0; i < 4; ++i) {
            const float* xp = s_lds + (kl0 + 76 + i)*32 + b0;
            float4 xa = *(const float4*)xp;
            float4 xb = *(const float4*)(xp + 4);
            FMA8(xa, xb, wbuf[i]);
        }

        // ---- combine ----
        __syncthreads();
        if (ksub) {
#pragma unroll
            for (int i = 0; i < 8; ++i)
                *(float4*)(s_lds + (ksub-1)*4096 + (b0 + i)*128 + jq*4) = a[i];
        }
        __syncthreads();
        if (!ksub) {
            float* zp2 = ws + OFF_ZP2;
#pragma unroll
            for (int i = 0; i < 8; ++i) {
                float4 r0 = *(const float4*)(s_lds +         (b0 + i)*128 + jq*4);
                float4 r1 = *(const float4*)(s_lds +  4096 + (b0 + i)*128 + jq*4);
                float4 r2 = *(const float4*)(s_lds +  8192 + (b0 + i)*128 + jq*4);
                a[i].x += r0.x + r1.x + r2.x; a[i].y += r0.y + r1.y + r2.y;
                a[i].z += r0.z + r1.z + r2.z; a[i].w += r0.w + r1.w + r2.w;
                *(float4*)(zp2 + (size_t)(ksp*32 + b0 + i)*4096 + j) = a[i];
            }
        }
    }
}

// ================================================================
// Phase kernel P2: blocks 0-31 lstm1-gates+attention+ctx(t)
//   | 32-63 lstm2-gates(t-1) | 64-103 mel(t-2) | 104 stop(t-2)
// (R5-verified unrolled chains; mel re-split 10->40 blocks, 96-chain.)
// ================================================================
__global__ void __launch_bounds__(1024) kernel_P2(
    const float* __restrict__ mp, const float* __restrict__ l1b, const float* __restrict__ l2b,
    const float* __restrict__ wq, const float* __restrict__ vvec,
    const float* __restrict__ lconv, const float* __restrict__ ldense,
    const float* __restrict__ fw, const float* __restrict__ fb,
    const float* __restrict__ sw, const float* __restrict__ sb,
    float* __restrict__ ws, float* __restrict__ out, int t)
{
    __shared__ float s_attw[200], s_cum[200];
    __shared__ float s_hid[1024], s_q[128], s_ex[200], s_den[1];
    __shared__ float s_co[200*33];
    __shared__ float s_red[1024];
    const int tid = threadIdx.x, bid = blockIdx.x;
    float* in1m = ws + OFF_IN1T - 8192;
    float* in2T = ws + OFF_IN2T;
    float* zp1  = ws + OFF_ZP1;
    float* zp2  = ws + OFF_ZP2;
    float* ctxp = ws + OFF_CTXP;
    float* h2bb = ws + OFF_H2B;
    float* c1a  = ws + OFF_C1;
    float* c2a  = ws + OFF_C2;
    float* attw = ws + OFF_ATTW;
    float* cum  = ws + OFF_CUM;
    const float* pm = ws + OFF_PM;

    if (bid < 32) {
        if (t >= TSTEPS) return;
        const int b = bid;
        {   // LSTM1 gates
            int u = tid;
            float zi = l1b[u], zf = l1b[1024+u], zg = l1b[2048+u], zo = l1b[3072+u];
#pragma unroll
            for (int kc = 0; kc < KSP1; ++kc) {
                const float* zr = zp1 + (size_t)(kc*32 + b)*4096;
                zi += zr[u]; zf += zr[1024+u]; zg += zr[2048+u]; zo += zr[3072+u];
            }
            float c = sigf(zf)*c1a[b*1024+u] + sigf(zi)*tanhf_(zg);
            float h = sigf(zo)*tanhf_(c);
            c1a[b*1024+u] = c;
            s_hid[u] = h;
            in1m[(768+u)*32 + b] = h;       // for gemv1(t+1)
            in2T[u*32 + b] = h;             // for gemv2(t)
        }
        if (tid < 200) { s_attw[tid] = attw[b*200 + tid]; s_cum[tid] = cum[b*200 + tid]; }
        __syncthreads();
        {   // q partials: 8 k-strips x 128 a
            int a = tid & 127, kq = tid >> 7;
            float s = 0.f;
#pragma unroll 8
            for (int k = kq*128; k < kq*128 + 128; ++k)
                s = fmaf(s_hid[k], wq[k*128 + a], s);
            s_red[tid] = s;
        }
        __syncthreads();
        if (tid < 128) {
            float s = 0.f;
#pragma unroll
            for (int q = 0; q < 8; ++q) s += s_red[q*128 + tid];
            s_q[tid] = tanhf_(s);
        }
        // location conv (t-1 attw/cum from LDS)
        for (int idx = tid; idx < 6400; idx += 1024) {
            int tl = idx >> 5, f = idx & 31;
            float s = 0.f;
            for (int dw = 0; dw < 31; ++dw) {
                int tg = tl - 15 + dw;
                if (tg >= 0 && tg < 200) {
                    s = fmaf(s_attw[tg], lconv[(dw*2+0)*32 + f], s);
                    s = fmaf(s_cum[tg],  lconv[(dw*2+1)*32 + f], s);
                }
            }
            s_co[tl*33 + f] = s;
        }
        __syncthreads();
        // energies: 200 t x 4 lanes x 32 a
        if (tid < 800) {
            int tl = tid >> 2, aq = tid & 3;
            const float* pmrow = pm + (b*200 + tl)*128;
            float e = 0.f;
#pragma unroll 2
            for (int a = aq*32; a < aq*32 + 32; ++a) {
                float s = 0.f;
#pragma unroll
                for (int f = 0; f < 32; ++f) s = fmaf(s_co[tl*33 + f], ldense[f*128 + a], s);
                float en = tanhf_(s_q[a] + tanhf_(s) + pmrow[a]);
                e = fmaf(en, vvec[a], e);
            }
            e += __shfl_xor(e, 1, 4);
            e += __shfl_xor(e, 2, 4);
            if (aq == 0) s_ex[tl] = __expf(e);   // |e| <= ||v||_1 ~ 5: exp safe
        }
        __syncthreads();
        if (tid < 64) {
            float s = 0.f;
            for (int i = tid; i < 200; i += 64) s += s_ex[i];
            for (int off = 32; off; off >>= 1) s += __shfl_down(s, off, 64);
            if (tid == 0) s_den[0] = s;
        }
        __syncthreads();
        if (tid < 200) {
            float w = s_ex[tid] / s_den[0];
            s_attw[tid] = w;
            attw[b*200 + tid] = w;
            cum[b*200 + tid] = s_cum[tid] + w;
            out[OUT_ALIGN + (b*400 + t)*200 + tid] = w;
        }
        __syncthreads();
        {   // context = att_w @ memory
            int d = tid & 511, th = tid >> 9;
            float s = 0.f;
#pragma unroll 10
            for (int tt = th*100; tt < th*100 + 100; ++tt)
                s = fmaf(s_attw[tt], mp[(b*200 + tt)*512 + d], s);
            s_red[tid] = s;
        }
        __syncthreads();
        if (tid < 512) {
            float cv = s_red[tid] + s_red[512 + tid];
            ctxp[(size_t)(t & 3)*16384 + b*512 + tid] = cv;
            in1m[(256 + tid)*32 + b] = cv;     // for gemv1(t+1)
            in2T[(1024 + tid)*32 + b] = cv;    // for gemv2(t)
        }
    } else if (bid < 64) {
        if (t < 1 || t > TSTEPS) return;
        // LSTM2 gates, step t-1
        const int b = bid - 32, t1 = t - 1;
        float* h2b = h2bb + (size_t)(t1 & 1)*32768;
        int u = tid;
        float zi = l2b[u], zf = l2b[1024+u], zg = l2b[2048+u], zo = l2b[3072+u];
#pragma unroll
        for (int kc = 0; kc < KSP2; ++kc) {
            const float* zr = zp2 + (size_t)(kc*32 + b)*4096;
            zi += zr[u]; zf += zr[1024+u]; zg += zr[2048+u]; zo += zr[3072+u];
        }
        float c = sigf(zf)*c2a[b*1024+u] + sigf(zi)*tanhf_(zg);
        float h = sigf(zo)*tanhf_(c);
        c2a[b*1024+u] = c;
        in2T[(1536+u)*32 + b] = h;      // for gemv2(t)
        h2b[u*32 + b] = h;              // for mel/stop(t-1) later
    } else if (bid < 104) {
        if (t < 2) return;
        // mel, step t-2 : 40 blocks x 2 mel-cols, 16 kh x 96 k (short chains)
        const int t2 = t - 2;
        const int mc = bid - 64;
        const int m_l = tid & 1, b = (tid >> 1) & 31, khm = tid >> 6;   // khm 0..15
        const int m = mc*2 + m_l;
        const float* cp = ctxp + (size_t)((t2 & 3)*32 + b)*512;
        const float* h2b = h2bb + (size_t)(t2 & 1)*32768;
        float s = 0.f;
#pragma unroll 8
        for (int k = khm*96; k < khm*96 + 96; ++k) {
            float dv = (k < 1024) ? h2b[k*32 + b] : cp[k - 1024];
            s = fmaf(dv, fw[k*80 + m], s);
        }
        s_red[tid] = s;   // tid = khm*64 + b*2 + m_l
        __syncthreads();
        if (tid < 64) {
            float v = 0.f;
#pragma unroll
            for (int k2 = 0; k2 < 16; ++k2) v += s_red[k2*64 + tid];
            int b2 = tid >> 1, m2 = mc*2 + (tid & 1);
            out[(b2*80 + m2)*400 + t2] = v + fb[m2];
        }
    } else {
        if (t < 2) return;
        // stop gate, step t-2
        const int t2 = t - 2;
        const int b = tid >> 5, kh = tid & 31;
        const float* cp = ctxp + (size_t)((t2 & 3)*32 + b)*512;
        const float* h2b = h2bb + (size_t)(t2 & 1)*32768;
        float s = 0.f;
#pragma unroll 8
        for (int k = kh*48; k < kh*48 + 48; ++k) {
            float dv = (k < 1024) ? h2b[k*32 + b] : cp[k - 1024];
            s = fmaf(dv, sw[k], s);
        }
        s_red[b*32 + kh] = s;
        __syncthreads();
        if (tid < 32) {
            float z = 0.f;
#pragma unroll
            for (int i = 0; i < 32; ++i) z += s_red[tid*32 + i];
            out[OUT_GATE + tid*400 + t2] = sigf(z + sb[0]);
        }
    }
}

extern "C" void kernel_launch(void* const* d_in, const int* in_sizes, int n_in,
                              void* d_out, int out_size, void* d_ws, size_t ws_size,
                              hipStream_t stream) {
    (void)in_sizes; (void)n_in; (void)out_size;
    const float* mp    = (const float*)d_in[0];
    const float* dec   = (const float*)d_in[1];
    const float* pw0   = (const float*)d_in[2];
    const float* pb0   = (const float*)d_in[3];
    const float* pw1   = (const float*)d_in[4];
    const float* pb1   = (const float*)d_in[5];
    const float* l1k   = (const float*)d_in[6];
    const float* l1r   = (const float*)d_in[7];
    const float* l1b   = (const float*)d_in[8];
    const float* l2k   = (const float*)d_in[9];
    const float* l2r   = (const float*)d_in[10];
    const float* l2b   = (const float*)d_in[11];
    const float* wq    = (const float*)d_in[12];
    const float* wm    = (const float*)d_in[13];
    const float* vvec  = (const float*)d_in[14];
    const float* lconv = (const float*)d_in[15];
    const float* ldns  = (const float*)d_in[16];
    const float* fw    = (const float*)d_in[17];
    const float* fb    = (const float*)d_in[18];
    const float* sw    = (const float*)d_in[19];
    const float* sb    = (const float*)d_in[20];
    float* ws  = (float*)d_ws;
    float* out = (float*)d_out;

    if (ws_size < (size_t)WS_FLOATS * sizeof(float)) return;

    prenet_kernel<<<dim3(400, 32), 256, 0, stream>>>(dec, pw0, pb0, pw1, pb1, ws);
    pmem_kernel  <<<dim3(200, 32), 128, 0, stream>>>(mp, wm, ws);
    zero_kernel  <<<256, 256, 0, stream>>>(ws);

    // t=0..399: full steps; t=400: gemv2(399)+gates2(399)+mel/stop(398);
    // t=401 (P2 only): mel/stop(399).
    for (int t = 0; t <= TSTEPS; ++t) {
        kernel_P1<<<480, 512, 0, stream>>>(l1k, l1r, l2k, l2r, ws, t);
        kernel_P2<<<105, 1024, 0, stream>>>(mp, l1b, l2b, wq, vvec, lconv, ldns,
                                            fw, fb, sw, sb, ws, out, t);
    }
    kernel_P2<<<105, 1024, 0, stream>>>(mp, l1b, l2b, wq, vvec, lconv, ldns,
                                        fw, fb, sw, sb, ws, out, TSTEPS + 1);
}

// Round 11
// 75760.962 us; speedup vs baseline: 6.1940x; 1.2975x over previous
//
#include <hip/hip_runtime.h>
#include <math.h>

// ---------------- problem constants ----------------
#define TSTEPS 400

// GEMV1: K1=1792 (x 0..255 bf16 | ctx 256..767 | h1 768..1791), W split at 768
//   224 blocks = 32 colgrp(128 cols) x 7 ksp(256 k = 4 ksub x 64)
// GEMV2: K2=2560 (h1 0..1023 | ctx 1024..1535 | h2 1536..2559), W split at 1536
//   256 blocks = 32 colgrp(128 cols) x 8 ksp(320 k = 4 ksub x 80)
#define KSP1 7
#define KSP2 8

// ---------------- workspace layout (float offsets) ----------------
#define OFF_XPRE  0u          // prenet out, BF16 [t][k][b]: 400*256*32 ushort = 1,638,400 float-slots
#define OFF_PM    1638400u    // tanh(memory@wm) fp32 [b][t][128]  (819,200)
#define OFF_IN1T  2457600u    // lstm1 input rows 256..1791, [(k-256)][b] (49,152)
#define OFF_IN2T  2506752u    // lstm2 input rows [k][b] (81,920)
#define OFF_ZP1   2588672u    // gemv1 partials [7][32][4096] (917,504)
#define OFF_ZP2   3506176u    // gemv2 partials [8][32][4096] (1,048,576)
#define OFF_CTXP  4554752u    // ctx 4-deep buffer [t&3][b][512] (65,536)
#define OFF_H2B   4620288u    // h2 2-deep buffer [parity][k][b] (65,536)
#define OFF_C1    4685824u    // c1 [b][1024] (32,768)
#define OFF_C2    4718592u    // c2 (32,768)
#define OFF_ATTW  4751360u    // att_w [b][200] (6,400)
#define OFF_CUM   4757760u    // att_w_cum (6,400)
#define WS_FLOATS 4764160u    // 19.06 MB (<= proven-available 24.9 MB)

// output layout (floats)
#define OUT_GATE  1024000   // 32*80*400
#define OUT_ALIGN 1036800   // + 32*400

__device__ __forceinline__ float sigf(float x)   { return 1.f / (1.f + __expf(-x)); }
__device__ __forceinline__ float tanhf_(float x) { return 1.f - 2.f / (__expf(2.f*x) + 1.f); }

// ---------------- P1: prenet for all 400 frames -> bf16 [t][k][b] ----------------
__global__ void __launch_bounds__(256) prenet_kernel(
    const float* __restrict__ dec, const float* __restrict__ w0, const float* __restrict__ b0,
    const float* __restrict__ w1, const float* __restrict__ b1, float* __restrict__ ws)
{
    __shared__ float s_in[80];
    __shared__ float s_h0[256];
    int t = blockIdx.x, b = blockIdx.y, tid = threadIdx.x;
    if (tid < 80) s_in[tid] = (t == 0) ? 0.f : dec[b*32000 + tid*400 + (t-1)];
    __syncthreads();
    float s = b0[tid];
    for (int m = 0; m < 80; ++m) s = fmaf(s_in[m], w0[m*256 + tid], s);
    s_h0[tid] = fmaxf(s, 0.f);
    __syncthreads();
    float s2 = b1[tid];
    for (int k = 0; k < 256; ++k) s2 = fmaf(s_h0[k], w1[k*256 + tid], s2);
    float v = fmaxf(s2, 0.f);
    unsigned u = __float_as_uint(v);
    u += 0x7fffu + ((u >> 16) & 1u);                     // RNE to bf16
    ((unsigned short*)(ws + OFF_XPRE))[(size_t)t*8192 + tid*32 + b] = (unsigned short)(u >> 16);
}

// ---------------- P2: processed_memory = tanh(memory @ wm), fp32 ----------------
__global__ void __launch_bounds__(128) pmem_kernel(
    const float* __restrict__ mp, const float* __restrict__ wm, float* __restrict__ ws)
{
    int t = blockIdx.x, b = blockIdx.y, a = threadIdx.x;
    const float* mrow = mp + (b*200 + t)*512;
    float s = 0.f;
    for (int d = 0; d < 512; ++d) s = fmaf(mrow[d], wm[d*128 + a], s);
    ws[OFF_PM + (b*200 + t)*128 + a] = tanhf_(s);
}

// ---------------- P3: zero recurrent state ----------------
__global__ void __launch_bounds__(256) zero_kernel(float* __restrict__ ws)
{
    int gid = blockIdx.x*256 + threadIdx.x, gsz = gridDim.x*256;
    for (int i = gid; i < 49152; i += gsz) ws[OFF_IN1T + i] = 0.f;
    for (int i = gid; i < 81920; i += gsz) ws[OFF_IN2T + i] = 0.f;
    for (int i = gid; i < 32768; i += gsz) { ws[OFF_C1 + i] = 0.f; ws[OFF_C2 + i] = 0.f; }
    for (int i = gid; i < 65536; i += gsz) { ws[OFF_CTXP + i] = 0.f; ws[OFF_H2B + i] = 0.f; }
    for (int i = gid; i < 6400;  i += gsz) { ws[OFF_ATTW + i] = 0.f; ws[OFF_CUM + i] = 0.f; }
}

#define FMA8(XA, XB, W)                                                                               \
    a[0].x = fmaf(XA.x, W.x, a[0].x); a[0].y = fmaf(XA.x, W.y, a[0].y); a[0].z = fmaf(XA.x, W.z, a[0].z); a[0].w = fmaf(XA.x, W.w, a[0].w); \
    a[1].x = fmaf(XA.y, W.x, a[1].x); a[1].y = fmaf(XA.y, W.y, a[1].y); a[1].z = fmaf(XA.y, W.z, a[1].z); a[1].w = fmaf(XA.y, W.w, a[1].w); \
    a[2].x = fmaf(XA.z, W.x, a[2].x); a[2].y = fmaf(XA.z, W.y, a[2].y); a[2].z = fmaf(XA.z, W.z, a[2].z); a[2].w = fmaf(XA.z, W.w, a[2].w); \
    a[3].x = fmaf(XA.w, W.x, a[3].x); a[3].y = fmaf(XA.w, W.y, a[3].y); a[3].z = fmaf(XA.w, W.z, a[3].z); a[3].w = fmaf(XA.w, W.w, a[3].w); \
    a[4].x = fmaf(XB.x, W.x, a[4].x); a[4].y = fmaf(XB.x, W.y, a[4].y); a[4].z = fmaf(XB.x, W.z, a[4].z); a[4].w = fmaf(XB.x, W.w, a[4].w); \
    a[5].x = fmaf(XB.y, W.x, a[5].x); a[5].y = fmaf(XB.y, W.y, a[5].y); a[5].z = fmaf(XB.y, W.z, a[5].z); a[5].w = fmaf(XB.y, W.w, a[5].w); \
    a[6].x = fmaf(XB.z, W.x, a[6].x); a[6].y = fmaf(XB.z, W.y, a[6].y); a[6].z = fmaf(XB.z, W.z, a[6].z); a[6].w = fmaf(XB.z, W.w, a[6].w); \
    a[7].x = fmaf(XB.w, W.x, a[7].x); a[7].y = fmaf(XB.w, W.y, a[7].y); a[7].z = fmaf(XB.w, W.z, a[7].z); a[7].w = fmaf(XB.w, W.w, a[7].w)

// ================================================================
// Phase kernel P1: gemv1(t) [blocks 0..223] || gemv2(t-1) [blocks 224..479]
// 512 thr = 32 jq(4 cols, 128/block) x 4 bgrp(8 b) x 4 ksub.
// Activation slice staged in LDS (vmcnt queue = weight stream only);
// weights manually prefetched 4-deep. LDS union: x-stage then acc-combine.
// ================================================================
__global__ void __launch_bounds__(512, 4) kernel_P1(
    const float* __restrict__ l1k, const float* __restrict__ l1r,
    const float* __restrict__ l2k, const float* __restrict__ l2r,
    float* __restrict__ ws, int t)
{
    __shared__ float s_lds[12288];   // union: x-stage (<=10240) | acc 3x4096
    const int tid = threadIdx.x, bid = blockIdx.x;
    const int jq = tid & 31, bgrp = (tid >> 5) & 3, ksub = tid >> 7;
    const int b0 = bgrp*8;
    float4 a[8];
#pragma unroll
    for (int i = 0; i < 8; ++i) a[i] = make_float4(0.f, 0.f, 0.f, 0.f);

    if (bid < 224) {
        if (t >= TSTEPS) return;
        // -------- gemv1(t): block = 128 cols x 256 k --------
        const int colgrp = bid & 31, ksp = bid >> 5;
        const int j = colgrp*128 + jq*4;

        // ---- stage x slice (256 k x 32 b floats = 8192) into LDS ----
        if (ksp == 0) {
            // bf16 prenet frame -> f32
            const uint4* src = (const uint4*)((const unsigned short*)(ws + OFF_XPRE) + (size_t)t*8192);
            for (int i = tid; i < 1024; i += 512) {
                uint4 p = src[i];
                float* d = s_lds + i*8;
                d[0] = __uint_as_float(p.x << 16); d[1] = __uint_as_float(p.x & 0xffff0000u);
                d[2] = __uint_as_float(p.y << 16); d[3] = __uint_as_float(p.y & 0xffff0000u);
                d[4] = __uint_as_float(p.z << 16); d[5] = __uint_as_float(p.z & 0xffff0000u);
                d[6] = __uint_as_float(p.w << 16); d[7] = __uint_as_float(p.w & 0xffff0000u);
            }
        } else {
            const float4* src = (const float4*)(ws + OFF_IN1T - 8192 + (size_t)ksp*256*32);
            float4* dst = (float4*)s_lds;
            for (int i = tid; i < 2048; i += 512) dst[i] = src[i];
        }
        __syncthreads();

        // ---- FMA loop: 64 k per ksub, 4-deep weight prefetch ----
        // 64-k ranges are 64-aligned; the 768 boundary is 64-aligned -> no straddle
        const int kl0 = ksub*64;                    // local k in [0,256)
        const int kg0 = ksp*256 + kl0;              // global k
        const float* wb = (kg0 < 768) ? (l1k + (size_t)kg0*4096 + j)
                                      : (l1r + (size_t)(kg0 - 768)*4096 + j);
        float4 wbuf[4];
#pragma unroll
        for (int i = 0; i < 4; ++i) wbuf[i] = *(const float4*)(wb + (size_t)i*4096);
        for (int kk = 0; kk < 60; kk += 4) {
            float4 wn[4];
#pragma unroll
            for (int i = 0; i < 4; ++i) wn[i] = *(const float4*)(wb + (size_t)(kk + 4 + i)*4096);
#pragma unroll
            for (int i = 0; i < 4; ++i) {
                const float* xp = s_lds + (kl0 + kk + i)*32 + b0;
                float4 xa = *(const float4*)xp;
                float4 xb = *(const float4*)(xp + 4);
                FMA8(xa, xb, wbuf[i]);
            }
#pragma unroll
            for (int i = 0; i < 4; ++i) wbuf[i] = wn[i];
        }
#pragma unroll
        for (int i = 0; i < 4; ++i) {
            const float* xp = s_lds + (kl0 + 60 + i)*32 + b0;
            float4 xa = *(const float4*)xp;
            float4 xb = *(const float4*)(xp + 4);
            FMA8(xa, xb, wbuf[i]);
        }

        // ---- combine ksubs via LDS (reuse s_lds after barrier) ----
        __syncthreads();
        if (ksub) {
#pragma unroll
            for (int i = 0; i < 8; ++i)
                *(float4*)(s_lds + (ksub-1)*4096 + (b0 + i)*128 + jq*4) = a[i];
        }
        __syncthreads();
        if (!ksub) {
            float* zp1 = ws + OFF_ZP1;
#pragma unroll
            for (int i = 0; i < 8; ++i) {
                float4 r0 = *(const float4*)(s_lds +         (b0 + i)*128 + jq*4);
                float4 r1 = *(const float4*)(s_lds +  4096 + (b0 + i)*128 + jq*4);
                float4 r2 = *(const float4*)(s_lds +  8192 + (b0 + i)*128 + jq*4);
                a[i].x += r0.x + r1.x + r2.x; a[i].y += r0.y + r1.y + r2.y;
                a[i].z += r0.z + r1.z + r2.z; a[i].w += r0.w + r1.w + r2.w;
                *(float4*)(zp1 + (size_t)(ksp*32 + b0 + i)*4096 + j) = a[i];
            }
        }
    } else {
        if (t < 1 || t > TSTEPS) return;
        // -------- gemv2(t-1): block = 128 cols x 320 k --------
        const int g = bid - 224;
        const int colgrp = g & 31, ksp = g >> 5;
        const int j = colgrp*128 + jq*4;

        // ---- stage x slice (320 k x 32 b = 10240 floats) into LDS ----
        {
            const float4* src = (const float4*)(ws + OFF_IN2T + (size_t)ksp*320*32);
            float4* dst = (float4*)s_lds;
            for (int i = tid; i < 2560; i += 512) dst[i] = src[i];
        }
        __syncthreads();

        // ---- FMA loop: 80 k per ksub, 4-deep weight prefetch ----
        // 80-k chunks can straddle the 1536 split -> per-load row select
        const int kl0 = ksub*80;                    // local k in [0,320)
        const int kg0 = ksp*320 + kl0;              // global k
        float4 wbuf[4];
#pragma unroll
        for (int i = 0; i < 4; ++i) {
            int kg = kg0 + i;
            const float* wr = (kg < 1536) ? (l2k + (size_t)kg*4096)
                                          : (l2r + (size_t)(kg - 1536)*4096);
            wbuf[i] = *(const float4*)(wr + j);
        }
        for (int kk = 0; kk < 76; kk += 4) {
            float4 wn[4];
#pragma unroll
            for (int i = 0; i < 4; ++i) {
                int kg = kg0 + kk + 4 + i;
                const float* wr = (kg < 1536) ? (l2k + (size_t)kg*4096)
                                              : (l2r + (size_t)(kg - 1536)*4096);
                wn[i] = *(const float4*)(wr + j);
            }
#pragma unroll
            for (int i = 0; i < 4; ++i) {
                const float* xp = s_lds + (kl0 + kk + i)*32 + b0;
                float4 xa = *(const float4*)xp;
                float4 xb = *(const float4*)(xp + 4);
                FMA8(xa, xb, wbuf[i]);
            }
#pragma unroll
            for (int i = 0; i < 4; ++i) wbuf[i] = wn[i];
        }
#pragma unroll
        for (int i = 0; i < 4; ++i) {
            const float* xp = s_lds + (kl0 + 76 + i)*32 + b0;
            float4 xa = *(const float4*)xp;
            float4 xb = *(const float4*)(xp + 4);
            FMA8(xa, xb, wbuf[i]);
        }

        // ---- combine ----
        __syncthreads();
        if (ksub) {
#pragma unroll
            for (int i = 0; i < 8; ++i)
                *(float4*)(s_lds + (ksub-1)*4096 + (b0 + i)*128 + jq*4) = a[i];
        }
        __syncthreads();
        if (!ksub) {
            float* zp2 = ws + OFF_ZP2;
#pragma unroll
            for (int i = 0; i < 8; ++i) {
                float4 r0 = *(const float4*)(s_lds +         (b0 + i)*128 + jq*4);
                float4 r1 = *(const float4*)(s_lds +  4096 + (b0 + i)*128 + jq*4);
                float4 r2 = *(const float4*)(s_lds +  8192 + (b0 + i)*128 + jq*4);
                a[i].x += r0.x + r1.x + r2.x; a[i].y += r0.y + r1.y + r2.y;
                a[i].z += r0.z + r1.z + r2.z; a[i].w += r0.w + r1.w + r2.w;
                *(float4*)(zp2 + (size_t)(ksp*32 + b0 + i)*4096 + j) = a[i];
            }
        }
    }
}

// ================================================================
// Phase kernel P2: blocks 0-31 lstm1-gates+attention+ctx(t)
//                  | 32-63 lstm2-gates(t-1) | 64-73 mel(t-2) | 74 stop(t-2)
// ================================================================
__global__ void __launch_bounds__(1024) kernel_P2(
    const float* __restrict__ mp, const float* __restrict__ l1b, const float* __restrict__ l2b,
    const float* __restrict__ wq, const float* __restrict__ vvec,
    const float* __restrict__ lconv, const float* __restrict__ ldense,
    const float* __restrict__ fw, const float* __restrict__ fb,
    const float* __restrict__ sw, const float* __restrict__ sb,
    float* __restrict__ ws, float* __restrict__ out, int t)
{
    __shared__ float s_attw[200], s_cum[200];
    __shared__ float s_hid[1024], s_q[128], s_ex[200], s_den[1];
    __shared__ float s_co[200*33];
    __shared__ float s_red[1024];
    const int tid = threadIdx.x, bid = blockIdx.x;
    float* in1m = ws + OFF_IN1T - 8192;
    float* in2T = ws + OFF_IN2T;
    float* zp1  = ws + OFF_ZP1;
    float* zp2  = ws + OFF_ZP2;
    float* ctxp = ws + OFF_CTXP;
    float* h2bb = ws + OFF_H2B;
    float* c1a  = ws + OFF_C1;
    float* c2a  = ws + OFF_C2;
    float* attw = ws + OFF_ATTW;
    float* cum  = ws + OFF_CUM;
    const float* pm = ws + OFF_PM;

    if (bid < 32) {
        if (t >= TSTEPS) return;
        const int b = bid;
        {   // LSTM1 gates
            int u = tid;
            float zi = l1b[u], zf = l1b[1024+u], zg = l1b[2048+u], zo = l1b[3072+u];
#pragma unroll
            for (int kc = 0; kc < KSP1; ++kc) {
                const float* zr = zp1 + (size_t)(kc*32 + b)*4096;
                zi += zr[u]; zf += zr[1024+u]; zg += zr[2048+u]; zo += zr[3072+u];
            }
            float c = sigf(zf)*c1a[b*1024+u] + sigf(zi)*tanhf_(zg);
            float h = sigf(zo)*tanhf_(c);
            c1a[b*1024+u] = c;
            s_hid[u] = h;
            in1m[(768+u)*32 + b] = h;       // for gemv1(t+1)
            in2T[u*32 + b] = h;             // for gemv2(t)
        }
        if (tid < 200) { s_attw[tid] = attw[b*200 + tid]; s_cum[tid] = cum[b*200 + tid]; }
        __syncthreads();
        {   // q partials: 8 k-strips x 128 a
            int a = tid & 127, kq = tid >> 7;
            float s = 0.f;
            for (int k = kq*128; k < kq*128 + 128; ++k)
                s = fmaf(s_hid[k], wq[k*128 + a], s);
            s_red[tid] = s;
        }
        __syncthreads();
        if (tid < 128) {
            float s = 0.f;
#pragma unroll
            for (int q = 0; q < 8; ++q) s += s_red[q*128 + tid];
            s_q[tid] = tanhf_(s);
        }
        // location conv (t-1 attw/cum from LDS)
        for (int idx = tid; idx < 6400; idx += 1024) {
            int tl = idx >> 5, f = idx & 31;
            float s = 0.f;
            for (int dw = 0; dw < 31; ++dw) {
                int tg = tl - 15 + dw;
                if (tg >= 0 && tg < 200) {
                    s = fmaf(s_attw[tg], lconv[(dw*2+0)*32 + f], s);
                    s = fmaf(s_cum[tg],  lconv[(dw*2+1)*32 + f], s);
                }
            }
            s_co[tl*33 + f] = s;
        }
        __syncthreads();
        // energies: 200 t x 4 lanes x 32 a
        if (tid < 800) {
            int tl = tid >> 2, aq = tid & 3;
            const float* pmrow = pm + (b*200 + tl)*128;
            float e = 0.f;
            for (int a = aq*32; a < aq*32 + 32; ++a) {
                float s = 0.f;
#pragma unroll
                for (int f = 0; f < 32; ++f) s = fmaf(s_co[tl*33 + f], ldense[f*128 + a], s);
                float en = tanhf_(s_q[a] + tanhf_(s) + pmrow[a]);
                e = fmaf(en, vvec[a], e);
            }
            e += __shfl_xor(e, 1, 4);
            e += __shfl_xor(e, 2, 4);
            if (aq == 0) s_ex[tl] = __expf(e);   // |e| <= ||v||_1 ~ 5: exp safe
        }
        __syncthreads();
        if (tid < 64) {
            float s = 0.f;
            for (int i = tid; i < 200; i += 64) s += s_ex[i];
            for (int off = 32; off; off >>= 1) s += __shfl_down(s, off, 64);
            if (tid == 0) s_den[0] = s;
        }
        __syncthreads();
        if (tid < 200) {
            float w = s_ex[tid] / s_den[0];
            s_attw[tid] = w;
            attw[b*200 + tid] = w;
            cum[b*200 + tid] = s_cum[tid] + w;
            out[OUT_ALIGN + (b*400 + t)*200 + tid] = w;
        }
        __syncthreads();
        {   // context = att_w @ memory
            int d = tid & 511, th = tid >> 9;
            float s = 0.f;
            for (int tt = th*100; tt < th*100 + 100; ++tt)
                s = fmaf(s_attw[tt], mp[(b*200 + tt)*512 + d], s);
            s_red[tid] = s;
        }
        __syncthreads();
        if (tid < 512) {
            float cv = s_red[tid] + s_red[512 + tid];
            ctxp[(size_t)(t & 3)*16384 + b*512 + tid] = cv;
            in1m[(256 + tid)*32 + b] = cv;     // for gemv1(t+1)
            in2T[(1024 + tid)*32 + b] = cv;    // for gemv2(t)
        }
    } else if (bid < 64) {
        if (t < 1 || t > TSTEPS) return;
        // LSTM2 gates, step t-1
        const int b = bid - 32, t1 = t - 1;
        float* h2b = h2bb + (size_t)(t1 & 1)*32768;
        int u = tid;
        float zi = l2b[u], zf = l2b[1024+u], zg = l2b[2048+u], zo = l2b[3072+u];
#pragma unroll
        for (int kc = 0; kc < KSP2; ++kc) {
            const float* zr = zp2 + (size_t)(kc*32 + b)*4096;
            zi += zr[u]; zf += zr[1024+u]; zg += zr[2048+u]; zo += zr[3072+u];
        }
        float c = sigf(zf)*c2a[b*1024+u] + sigf(zi)*tanhf_(zg);
        float h = sigf(zo)*tanhf_(c);
        c2a[b*1024+u] = c;
        in2T[(1536+u)*32 + b] = h;      // for gemv2(t)
        h2b[u*32 + b] = h;              // for mel/stop(t-1) later
    } else if (bid < 74) {
        if (t < 2) return;
        // mel, step t-2 : 10 blocks x 8 mel-cols
        const int t2 = t - 2;
        const int mc = bid - 64;
        const int m_l = tid & 7, b = (tid >> 3) & 31, kh = tid >> 8;   // 4 kh x 384 k
        const int m = mc*8 + m_l;
        const float* cp = ctxp + (size_t)((t2 & 3)*32 + b)*512;
        const float* h2b = h2bb + (size_t)(t2 & 1)*32768;
        float s = 0.f;
        for (int k = kh*384; k < kh*384 + 384; ++k) {
            float dv = (k < 1024) ? h2b[k*32 + b] : cp[k - 1024];
            s = fmaf(dv, fw[k*80 + m], s);
        }
        s_red[tid] = s;
        __syncthreads();
        if (tid < 256) {
            float v4 = s_red[tid] + s_red[256+tid] + s_red[512+tid] + s_red[768+tid];
            int b2 = tid >> 3, m2 = mc*8 + (tid & 7);
            out[(b2*80 + m2)*400 + t2] = v4 + fb[m2];
        }
    } else {
        if (t < 2) return;
        // stop gate, step t-2
        const int t2 = t - 2;
        const int b = tid >> 5, kh = tid & 31;
        const float* cp = ctxp + (size_t)((t2 & 3)*32 + b)*512;
        const float* h2b = h2bb + (size_t)(t2 & 1)*32768;
        float s = 0.f;
        for (int k = kh*48; k < kh*48 + 48; ++k) {
            float dv = (k < 1024) ? h2b[k*32 + b] : cp[k - 1024];
            s = fmaf(dv, sw[k], s);
        }
        s_red[b*32 + kh] = s;
        __syncthreads();
        if (tid < 32) {
            float z = 0.f;
#pragma unroll
            for (int i = 0; i < 32; ++i) z += s_red[tid*32 + i];
            out[OUT_GATE + tid*400 + t2] = sigf(z + sb[0]);
        }
    }
}

extern "C" void kernel_launch(void* const* d_in, const int* in_sizes, int n_in,
                              void* d_out, int out_size, void* d_ws, size_t ws_size,
                              hipStream_t stream) {
    (void)in_sizes; (void)n_in; (void)out_size;
    const float* mp    = (const float*)d_in[0];
    const float* dec   = (const float*)d_in[1];
    const float* pw0   = (const float*)d_in[2];
    const float* pb0   = (const float*)d_in[3];
    const float* pw1   = (const float*)d_in[4];
    const float* pb1   = (const float*)d_in[5];
    const float* l1k   = (const float*)d_in[6];
    const float* l1r   = (const float*)d_in[7];
    const float* l1b   = (const float*)d_in[8];
    const float* l2k   = (const float*)d_in[9];
    const float* l2r   = (const float*)d_in[10];
    const float* l2b   = (const float*)d_in[11];
    const float* wq    = (const float*)d_in[12];
    const float* wm    = (const float*)d_in[13];
    const float* vvec  = (const float*)d_in[14];
    const float* lconv = (const float*)d_in[15];
    const float* ldns  = (const float*)d_in[16];
    const float* fw    = (const float*)d_in[17];
    const float* fb    = (const float*)d_in[18];
    const float* sw    = (const float*)d_in[19];
    const float* sb    = (const float*)d_in[20];
    float* ws  = (float*)d_ws;
    float* out = (float*)d_out;

    if (ws_size < (size_t)WS_FLOATS * sizeof(float)) return;

    prenet_kernel<<<dim3(400, 32), 256, 0, stream>>>(dec, pw0, pb0, pw1, pb1, ws);
    pmem_kernel  <<<dim3(200, 32), 128, 0, stream>>>(mp, wm, ws);
    zero_kernel  <<<256, 256, 0, stream>>>(ws);

    // t=0..399: full steps; t=400: gemv2(399)+gates2(399)+mel/stop(398);
    // t=401: mel/stop(399) only (P1 has no work at 401).
    for (int t = 0; t <= TSTEPS; ++t) {
        kernel_P1<<<480, 512, 0, stream>>>(l1k, l1r, l2k, l2r, ws, t);
        kernel_P2<<<75, 1024, 0, stream>>>(mp, l1b, l2b, wq, vvec, lconv, ldns,
                                           fw, fb, sw, sb, ws, out, t);
    }
    kernel_P2<<<75, 1024, 0, stream>>>(mp, l1b, l2b, wq, vvec, lconv, ldns,
                                       fw, fb, sw, sb, ws, out, TSTEPS + 1);
}